// Round 6
// baseline (400.155 us; speedup 1.0000x reference)
//
#include <hip/hip_runtime.h>
#include <math.h>

#define NCLS 80
#define NANC 18
#define NB 8
#define GG 76
#define SS (GG*GG)              // 5776
#define CHN (NCLS+6)            // 86
#define NCELL (NB*NANC*SS)      // 831744
#define FLAG_WORDS ((NCELL+31)/32)  // 25992
#define NT_MAX 240
#define TILE 76                 // one grid row per tile
#define LSTR 77                 // LDS row stride (floats): odd -> 16-bank spread on 2h rows
#define TPB 4                   // tiles per block (register-pipelined)
#define TGRP (GG/TPB)           // 19
#define NLOAD 7                 // ceil(1634/256)
#define TOT4 (CHN*(TILE/4))     // 1634 float4 per tile
#define PI_ 3.14159265358979323846

// ws layout (bytes): acc double[4]@0, cnt int[4]@32 (n_zero, n_win, ticket, pad),
// win int[240]@64, meta int4[240]@1024, lm uint2[240]@4864, flags@6784
#define WS_WIN   64
#define WS_META  1024
#define WS_LM    4864
#define WS_FLAGS 6784

__device__ __constant__ float d_ma[NANC][3] = {
  {1.5f, 2.0f, (float)(-PI_/3)}, {1.5f, 2.0f, (float)(-PI_/6)}, {1.5f, 2.0f, 0.0f},
  {1.5f, 2.0f, (float)(PI_/6)},  {1.5f, 2.0f, (float)(PI_/3)},  {1.5f, 2.0f, (float)(PI_/2)},
  {2.375f, 4.5f, (float)(-PI_/3)}, {2.375f, 4.5f, (float)(-PI_/6)}, {2.375f, 4.5f, 0.0f},
  {2.375f, 4.5f, (float)(PI_/6)},  {2.375f, 4.5f, (float)(PI_/3)},  {2.375f, 4.5f, (float)(PI_/2)},
  {5.0f, 3.5f, (float)(-PI_/3)}, {5.0f, 3.5f, (float)(-PI_/6)}, {5.0f, 3.5f, 0.0f},
  {5.0f, 3.5f, (float)(PI_/6)},  {5.0f, 3.5f, (float)(PI_/3)},  {5.0f, 3.5f, (float)(PI_/2)},
};

__device__ __forceinline__ float sigm(float x) { return 1.0f / (1.0f + expf(-x)); }
__device__ __forceinline__ float fsig(float x) {
  return __builtin_amdgcn_rcpf(1.0f + __expf(-x));
}

// ---------------- K1: zero ws + per-target decisions ----------------
__global__ __launch_bounds__(256) void k_prep(const float* __restrict__ tgt,
                                              unsigned* __restrict__ flags,
                                              int* __restrict__ win,
                                              int4* __restrict__ meta,
                                              uint2* __restrict__ lmout,
                                              int* __restrict__ cnt,
                                              double* __restrict__ acc, int nT) {
  __shared__ int s_key[NT_MAX], s_lab[NT_MAX];
  __shared__ int s_win[NT_MAX];
  __shared__ int s_zero;

  int t = threadIdx.x;
  uint4* f4 = (uint4*)flags;
  for (int i = t; i < FLAG_WORDS/4; i += 256) f4[i] = make_uint4(0,0,0,0);
  if (t < 4) { acc[t] = 0.0; cnt[t] = 0; }
  if (t == 0) s_zero = 0;
  __syncthreads();

  int bi = 0, gi = 0, gj = 0, bn = 0;
  unsigned cm = 0;
  if (t < nT) {
    float bf = tgt[t*7+0], lf = tgt[t*7+1];
    float gx = tgt[t*7+2] * (float)GG, gy = tgt[t*7+3] * (float)GG;
    float gw = tgt[t*7+4] * (float)GG, gh = tgt[t*7+5] * (float)GG;
    float ga = tgt[t*7+6];
    bi = (int)bf; gi = (int)gx; gj = (int)gy;
    int lab = (int)lf;
    float best = -1e30f;
    for (int a = 0; a < NANC; ++a) {
      float aw = d_ma[a][0], ah = d_ma[a][1], aa = d_ma[a][2];
      float inter = fminf(aw, gw) * fminf(ah, gh);
      float uni = aw*ah + 1e-16f + gw*gh - inter;
      float off = fabsf(aa - ga);
      float ar = inter / uni * fabsf(cosf(aa - ga));   // precise cosf: argmax stability
      if (ar > best) { best = ar; bn = a; }            // first-max wins (strict >)
      if (ar > 0.5f || (ar > 0.4f && off < (float)(PI_/12))) cm |= (1u << a);
    }
    s_key[t] = ((bi*NANC + bn)*GG + gj)*GG + gi;
    s_lab[t] = lab;
    s_win[t] = 0;
  }
  __syncthreads();

  if (t < nT) {
    for (int a = 0; a < NANC; ++a) {
      if (((cm >> a) & 1u) || a == bn) {
        int cell = ((bi*NANC + a)*GG + gj)*GG + gi;
        unsigned bit = 1u << (cell & 31);
        unsigned old = atomicOr(&flags[cell >> 5], bit);
        if (!(old & bit)) atomicAdd(&s_zero, 1);
      }
    }
    // winner = last target (max index) with this cell key (numpy last-write-wins)
    int key = s_key[t];
    bool winner = true;
    for (int t2 = t + 1; t2 < nT; ++t2) if (s_key[t2] == key) { winner = false; break; }
    if (winner) {
      s_win[t] = 1;
      unsigned long long lm0 = 0, lm1 = 0;
      for (int t2 = 0; t2 < nT; ++t2) if (s_key[t2] == key) {
        int L = s_lab[t2];
        if (L < 64) lm0 |= 1ull << L; else lm1 |= 1ull << (L - 64);
      }
      lmout[t] = make_uint2((unsigned)(lm0 & 0xffffffffull), (unsigned)(lm0 >> 32));
      meta[t] = make_int4(bi, bn, gi, gj | ((int)(lm1 & 0xffffu) << 16));
      win[t] = 1;
    } else {
      win[t] = 0;
    }
  }
  __syncthreads();
  if (t == 0) {
    int nw = 0;
    for (int i = 0; i < nT; ++i) nw += s_win[i];
    cnt[0] = s_zero; cnt[1] = nw;
  }
}

// ---------------- K2: transpose/decode + noobj focal + winner loss + finalize ----------------
__global__ __launch_bounds__(256) void k_main(const float* __restrict__ in,
                                              float* __restrict__ out,
                                              const unsigned* __restrict__ flags,
                                              const float* __restrict__ tgt,
                                              const int* __restrict__ win,
                                              const int4* __restrict__ meta,
                                              const uint2* __restrict__ lm,
                                              double* __restrict__ acc,
                                              int* __restrict__ cnt,
                                              int nT, int nblocks) {
  __shared__ float lds[CHN * LSTR];      // 26488 B
  __shared__ unsigned s_flags[12];
  __shared__ double wsum[4];
  int blk = blockIdx.x;
  int tgrp = blk % TGRP;
  int ba = blk / TGRP;
  int a = ba % NANC;
  float aw8 = d_ma[a][0]*8.0f, ah8 = d_ma[a][1]*8.0f, aa = d_ma[a][2];
  const float* plane_in = in + (size_t)ba*CHN*SS;
  float* plane_out = out + (size_t)ba*SS*CHN;
  int tile0 = tgrp*TPB;

  // flag words covering this block's 4 tiles (304 bits)
  int bit0 = ba*SS + tile0*TILE;
  int w0 = bit0 >> 5, boff = bit0 & 31;
  if (threadIdx.x < 12) s_flags[threadIdx.x] = flags[w0 + threadIdx.x];

  // prologue: issue tile0 staging loads
  float4 r[NLOAD];
  { const float* tin = plane_in + tile0*TILE;
    #pragma unroll
    for (int k = 0; k < NLOAD; ++k) {
      int i = threadIdx.x + k*256;
      if (i < TOT4) { int c = i/19, s4 = i - c*19;
        r[k] = *(const float4*)(tin + (size_t)c*SS + 4*s4); } }
  }

  // ---- per-winner loss (blocks < nT), wave 3 only, overlaps staging latency ----
  if (blk < nT && (threadIdx.x >> 6) == 3 && win[blk]) {
    int lane = threadIdx.x & 63;
    int4 m = meta[blk];
    int bi = m.x, bn = m.y, gi = m.z, gj = m.w & 0xffff;
    unsigned lmhi = ((unsigned)m.w) >> 16;
    uint2 l0 = lm[blk];
    const float* base = in + ((size_t)(bi*NANC + bn)*CHN)*SS + (size_t)gj*GG + gi;

    // class BCE: lane -> class lane; lanes 0..15 also class 64+lane
    float p1 = fsig(base[(size_t)(6 + lane)*SS]);
    float pl1 = fminf(fmaxf(p1, 1e-7f), 1.0f - 1e-7f);
    bool tc1 = (lane < 32) ? ((l0.x >> lane) & 1u) : ((l0.y >> (lane - 32)) & 1u);
    float csum = tc1 ? -__logf(pl1) : -__logf(1.0f - pl1);
    if (lane < 16) {
      float p2 = fsig(base[(size_t)(6 + 64 + lane)*SS]);
      float pl2 = fminf(fmaxf(p2, 1e-7f), 1.0f - 1e-7f);
      bool tc2 = (lmhi >> lane) & 1u;
      csum += tc2 ? -__logf(pl2) : -__logf(1.0f - pl2);
    }
    for (int off = 32; off; off >>= 1) csum += __shfl_down(csum, off);
    if (lane == 0) atomicAdd(&acc[3], (double)csum);

    if (lane == 32) {
      int t = blk;
      float gx = tgt[t*7+2] * (float)GG, gyv = tgt[t*7+3] * (float)GG;
      float gw = tgt[t*7+4] * (float)GG, gh = tgt[t*7+5] * (float)GG;
      float ga = tgt[t*7+6];
      float rx = base[0], ry = base[(size_t)SS], rw = base[2*(size_t)SS],
            rh = base[3*(size_t)SS], ra = base[4*(size_t)SS], rcf = base[5*(size_t)SS];
      float aw = d_ma[bn][0], ah = d_ma[bn][1], aav = d_ma[bn][2];
      float px = sigm(rx)*1.05f - 0.025f + (float)gi;
      float py = sigm(ry)*1.05f - 0.025f + (float)gj;
      float pw = expf(rw)*aw, ph = expf(rh)*ah;
      float pang = ra + aav;
      float p1x = px - pw*0.5f, p1y = py - ph*0.5f, p2x = px + pw*0.5f, p2y = py + ph*0.5f;
      float t1x = gx - gw*0.5f, t1y = gyv - gh*0.5f, t2x = gx + gw*0.5f, t2y = gyv + gh*0.5f;
      float w1 = p2x - p1x, h1 = p2y - p1y, w2 = t2x - t1x, h2 = t2y - t1y;
      float area1 = w1*h1, area2 = w2*h2;
      float c1x = (p1x+p2x)*0.5f, c1y = (p1y+p2y)*0.5f, c2x = (t1x+t2x)*0.5f, c2y = (t1y+t2y)*0.5f;
      float ix = fmaxf(fminf(p2x,t2x) - fmaxf(p1x,t1x), 0.0f);
      float iy = fmaxf(fminf(p2y,t2y) - fmaxf(p1y,t1y), 0.0f);
      float inter_area = ix*iy;
      float dcx = c2x - c1x, dcy = c2y - c1y;
      float inter_diag = dcx*dcx + dcy*dcy;
      float ox = fmaxf(fmaxf(p2x,t2x) - fminf(p1x,t1x), 0.0f);
      float oy = fmaxf(fmaxf(p2y,t2y) - fminf(p1y,t1y), 0.0f);
      float outer_diag = ox*ox + oy*oy;
      float uni = area1 + area2 - inter_area;
      float u = inter_diag / outer_diag;
      float iou = inter_area / uni;
      float da = atanf(w2/h2) - atanf(w1/h1);
      float v = (float)(4.0/(PI_*PI_)) * da * da;
      float alpha = v / (1.0f - iou + v);
      float ciou = fminf(fmaxf(iou - (u + alpha*v), -1.0f), 1.0f);
      float skew_iou = iou * fabsf(cosf(pang - ga));
      float skew = expf(1.0f - skew_iou) - 1.0f;
      float bscale = 2.0f - gw*gh/369664.0f;   // (8*76)^2
      float ciou_t = bscale * (1.0f - ciou);
      float ta = ga - aav;
      float d = fabsf(ra - ta);
      float sl1 = (d < 1.0f) ? 0.5f*d*d : d - 0.5f;
      float reg = sl1 + ciou_t;
      atomicAdd(&acc[2], (double)(reg * (skew / reg)));
      float pc = sigm(rcf);
      float pcl = fminf(fmaxf(pc, 1e-7f), 1.0f - 1e-7f);
      float om = 1.0f - pc;
      atomicAdd(&acc[1], (double)(-logf(pcl) * 0.25f * om * om));
    }
  }

  double fl = 0.0;
  for (int tt = 0; tt < TPB; ++tt) {
    int tile = tile0 + tt;
    __syncthreads();                     // prior store-loop LDS reads done
    #pragma unroll
    for (int k = 0; k < NLOAD; ++k) {
      int i = threadIdx.x + k*256;
      if (i < TOT4) {
        int c = i/19, s4 = i - c*19;
        float* p = &lds[c*LSTR + 4*s4];
        p[0] = r[k].x; p[1] = r[k].y; p[2] = r[k].z; p[3] = r[k].w;
      }
    }
    __syncthreads();
    if (tt + 1 < TPB) {                  // prefetch next tile into regs
      const float* tin = plane_in + (tile + 1)*TILE;
      #pragma unroll
      for (int k = 0; k < NLOAD; ++k) {
        int i = threadIdx.x + k*256;
        if (i < TOT4) { int c = i/19, s4 = i - c*19;
          r[k] = *(const float4*)(tin + (size_t)c*SS + 4*s4); } }
    }
    float gyf = (float)tile;
    float2* ob2 = (float2*)(plane_out + (size_t)tile*TILE*CHN);

    // main store loop: channels 6..85, branchless (2 x fsig per float2)
    for (int q = threadIdx.x; q < TILE*40; q += 256) {
      int s = q / 40;
      int h = q - s*40;                  // pair (6+2h, 7+2h)
      int row = 6 + 2*h;
      float v0 = lds[row*LSTR + s];
      float v1 = lds[row*LSTR + LSTR + s];
      ob2[s*43 + 3 + h] = make_float2(fsig(v0), fsig(v1));
    }
    // small loop: channels 0..5 (+ flag-gated noobj focal on conf), 228 items
    {
      int q = threadIdx.x;
      if (q < TILE*3) {
        int s = q / 3;
        int h = q - s*3;
        float v0 = lds[(2*h)*LSTR + s];
        float v1 = lds[(2*h)*LSTR + LSTR + s];
        float2 rr;
        if (h == 0) { rr.x = (fsig(v0)*1.05f - 0.025f + (float)s)*8.0f;
                      rr.y = (fsig(v1)*1.05f - 0.025f + gyf)*8.0f; }
        else if (h == 1) { rr.x = __expf(v0)*aw8; rr.y = __expf(v1)*ah8; }
        else {
          rr.x = v0 + aa;
          float p = fsig(v1);
          rr.y = p;
          int bidx = boff + tt*TILE + s;
          if (!((s_flags[bidx >> 5] >> (bidx & 31)) & 1u)) {
            float pcl = fminf(fmaxf(p, 1e-7f), 1.0f - 1e-7f);
            fl += (double)(-__logf(1.0f - pcl) * 0.75f * p * p);
          }
        }
        ob2[s*43 + h] = rr;
      }
    }
  }

  // block-reduce fl, then ticket finalize
  int lane = threadIdx.x & 63, wid = threadIdx.x >> 6;
  for (int off = 32; off; off >>= 1) fl += __shfl_down(fl, off);
  if (lane == 0) wsum[wid] = fl;
  __syncthreads();
  if (threadIdx.x == 0) {
    atomicAdd(&acc[0], wsum[0] + wsum[1] + wsum[2] + wsum[3]);
    __threadfence();
    unsigned tk = atomicAdd((unsigned*)&cnt[2], 1u);
    if (tk == (unsigned)(nblocks - 1)) {
      double a0 = atomicAdd(&acc[0], 0.0);
      double a1 = atomicAdd(&acc[1], 0.0);
      double a2 = atomicAdd(&acc[2], 0.0);
      double a3 = atomicAdd(&acc[3], 0.0);
      int c0 = atomicAdd(&cnt[0], 0);
      int c1 = atomicAdd(&cnt[1], 0);
      double n_obj = fmax((double)c1, 1.0);
      double n_noobj = fmax((double)(NCELL - c0), 1.0);
      double loss = a2/n_obj + 10.0*(a1/n_obj + a0/n_noobj) + a3/(n_obj*(double)NCLS);
      out[(size_t)NCELL*CHN] = (float)loss;
    }
  }
}

extern "C" void kernel_launch(void* const* d_in, const int* in_sizes, int n_in,
                              void* d_out, int out_size, void* d_ws, size_t ws_size,
                              hipStream_t stream) {
  const float* in  = (const float*)d_in[0];
  const float* tgt = (const float*)d_in[1];
  float* out = (float*)d_out;
  double* acc = (double*)d_ws;
  int* cnt = (int*)((char*)d_ws + 32);
  int* win = (int*)((char*)d_ws + WS_WIN);
  int4* meta = (int4*)((char*)d_ws + WS_META);
  uint2* lm = (uint2*)((char*)d_ws + WS_LM);
  unsigned* flags = (unsigned*)((char*)d_ws + WS_FLAGS);
  int nT = in_sizes[1] / 7;
  if (nT > NT_MAX) nT = NT_MAX;

  hipLaunchKernelGGL(k_prep, dim3(1), dim3(256), 0, stream,
                     tgt, flags, win, meta, lm, cnt, acc, nT);
  hipLaunchKernelGGL(k_main, dim3(NB*NANC*TGRP), dim3(256), 0, stream,
                     in, out, flags, tgt, win, meta, lm, acc, cnt,
                     nT, NB*NANC*TGRP);
}

// Round 7
// 209.537 us; speedup vs baseline: 1.9097x; 1.9097x over previous
//
#include <hip/hip_runtime.h>
#include <math.h>

#define NCLS 80
#define NANC 18
#define NB 8
#define GG 76
#define SS (GG*GG)              // 5776
#define CHN (NCLS+6)            // 86
#define NCELL (NB*NANC*SS)      // 831744
#define FLAG_WORDS ((NCELL+31)/32)  // 25992
#define NT_MAX 240
#define TILE 76                 // one grid row per tile
#define LSTR 77                 // LDS row stride (floats)
#define TPB 4                   // tiles per block (register-pipelined)
#define TGRP (GG/TPB)           // 19
#define NLOAD 7                 // ceil(1634/256)
#define TOT4 (CHN*(TILE/4))     // 1634 float4 per tile
#define NCONF4 (NCELL/4)        // 207936
#define NCONFBLK ((NCONF4+255)/256) // 813
#define PI_ 3.14159265358979323846

// ws layout (bytes): acc double[4]@0, cnt int[4]@32, win int[240]@64,
// meta int4[240]@1024, lm uint2[240]@4864, flags@6784
#define WS_WIN   64
#define WS_META  1024
#define WS_LM    4864
#define WS_FLAGS 6784

__device__ __constant__ float d_ma[NANC][3] = {
  {1.5f, 2.0f, (float)(-PI_/3)}, {1.5f, 2.0f, (float)(-PI_/6)}, {1.5f, 2.0f, 0.0f},
  {1.5f, 2.0f, (float)(PI_/6)},  {1.5f, 2.0f, (float)(PI_/3)},  {1.5f, 2.0f, (float)(PI_/2)},
  {2.375f, 4.5f, (float)(-PI_/3)}, {2.375f, 4.5f, (float)(-PI_/6)}, {2.375f, 4.5f, 0.0f},
  {2.375f, 4.5f, (float)(PI_/6)},  {2.375f, 4.5f, (float)(PI_/3)},  {2.375f, 4.5f, (float)(PI_/2)},
  {5.0f, 3.5f, (float)(-PI_/3)}, {5.0f, 3.5f, (float)(-PI_/6)}, {5.0f, 3.5f, 0.0f},
  {5.0f, 3.5f, (float)(PI_/6)},  {5.0f, 3.5f, (float)(PI_/3)},  {5.0f, 3.5f, (float)(PI_/2)},
};

__device__ __forceinline__ float sigm(float x) { return 1.0f / (1.0f + expf(-x)); }
__device__ __forceinline__ float fsig(float x) {
  return __builtin_amdgcn_rcpf(1.0f + __expf(-x));
}

// ---------------- K1: zero ws + per-target decisions (no `in` reads) ----------------
__global__ __launch_bounds__(256) void k_prep(const float* __restrict__ tgt,
                                              unsigned* __restrict__ flags,
                                              int* __restrict__ win,
                                              int4* __restrict__ meta,
                                              uint2* __restrict__ lmout,
                                              int* __restrict__ cnt,
                                              double* __restrict__ acc, int nT) {
  __shared__ int s_key[NT_MAX], s_lab[NT_MAX];
  __shared__ int s_win[NT_MAX];
  __shared__ int s_zero;

  int t = threadIdx.x;
  uint4* f4 = (uint4*)flags;
  for (int i = t; i < FLAG_WORDS/4; i += 256) f4[i] = make_uint4(0,0,0,0);
  if (t < 4) { acc[t] = 0.0; cnt[t] = 0; }
  if (t == 0) s_zero = 0;
  __syncthreads();

  int bi = 0, gi = 0, gj = 0, bn = 0;
  unsigned cm = 0;
  if (t < nT) {
    float bf = tgt[t*7+0], lf = tgt[t*7+1];
    float gx = tgt[t*7+2] * (float)GG, gy = tgt[t*7+3] * (float)GG;
    float gw = tgt[t*7+4] * (float)GG, gh = tgt[t*7+5] * (float)GG;
    float ga = tgt[t*7+6];
    bi = (int)bf; gi = (int)gx; gj = (int)gy;
    int lab = (int)lf;
    float best = -1e30f;
    for (int a = 0; a < NANC; ++a) {
      float aw = d_ma[a][0], ah = d_ma[a][1], aa = d_ma[a][2];
      float inter = fminf(aw, gw) * fminf(ah, gh);
      float uni = aw*ah + 1e-16f + gw*gh - inter;
      float off = fabsf(aa - ga);
      float ar = inter / uni * fabsf(cosf(aa - ga));   // precise cosf: argmax stability
      if (ar > best) { best = ar; bn = a; }            // first-max wins (strict >)
      if (ar > 0.5f || (ar > 0.4f && off < (float)(PI_/12))) cm |= (1u << a);
    }
    s_key[t] = ((bi*NANC + bn)*GG + gj)*GG + gi;
    s_lab[t] = lab;
    s_win[t] = 0;
  }
  __syncthreads();

  if (t < nT) {
    for (int a = 0; a < NANC; ++a) {
      if (((cm >> a) & 1u) || a == bn) {
        int cell = ((bi*NANC + a)*GG + gj)*GG + gi;
        unsigned bit = 1u << (cell & 31);
        unsigned old = atomicOr(&flags[cell >> 5], bit);
        if (!(old & bit)) atomicAdd(&s_zero, 1);
      }
    }
    // winner = last target (max index) with this cell key (numpy last-write-wins)
    int key = s_key[t];
    bool winner = true;
    for (int t2 = t + 1; t2 < nT; ++t2) if (s_key[t2] == key) { winner = false; break; }
    if (winner) {
      s_win[t] = 1;
      unsigned long long lm0 = 0, lm1 = 0;
      for (int t2 = 0; t2 < nT; ++t2) if (s_key[t2] == key) {
        int L = s_lab[t2];
        if (L < 64) lm0 |= 1ull << L; else lm1 |= 1ull << (L - 64);
      }
      lmout[t] = make_uint2((unsigned)(lm0 & 0xffffffffull), (unsigned)(lm0 >> 32));
      meta[t] = make_int4(bi, bn, gi, gj | ((int)(lm1 & 0xffffu) << 16));
      win[t] = 1;
    } else {
      win[t] = 0;
    }
  }
  __syncthreads();
  if (t == 0) {
    int nw = 0;
    for (int i = 0; i < nT; ++i) nw += s_win[i];
    cnt[0] = s_zero; cnt[1] = nw;
  }
}

// ---------------- K2: fused loss kernel ----------------
// blocks [0, nT): per-winner cls/reg/conf(t=1) terms.
// blocks [nT, nT+NCONFBLK): noobj focal over the conf-channel plane (flag-gated).
__global__ __launch_bounds__(256) void k_loss(const float* __restrict__ tgt,
                                              const float* __restrict__ in,
                                              const int* __restrict__ win,
                                              const int4* __restrict__ meta,
                                              const uint2* __restrict__ lm,
                                              const unsigned* __restrict__ flags,
                                              double* __restrict__ acc, int nT) {
  int blk = blockIdx.x;
  int tid = threadIdx.x;

  if (blk < nT) {
    int t = blk;
    if (!win[t]) return;
    int4 m = meta[t];
    int bi = m.x, bn = m.y, gi = m.z, gj = m.w & 0xffff;
    unsigned lmhi = ((unsigned)m.w) >> 16;
    uint2 l0 = lm[t];
    const float* base = in + ((size_t)(bi*NANC + bn)*CHN)*SS + (size_t)gj*GG + gi;

    float csum = 0.0f;
    if (tid < NCLS) {
      float p = fsig(base[(size_t)(6 + tid)*SS]);
      float pl = fminf(fmaxf(p, 1e-7f), 1.0f - 1e-7f);
      bool tc;
      if (tid < 32)      tc = (l0.x >> tid) & 1u;
      else if (tid < 64) tc = (l0.y >> (tid - 32)) & 1u;
      else               tc = (lmhi >> (tid - 64)) & 1u;
      csum = tc ? -__logf(pl) : -__logf(1.0f - pl);
    }
    for (int off = 32; off; off >>= 1) csum += __shfl_down(csum, off);
    if ((tid & 63) == 0 && tid < 128) atomicAdd(&acc[3], (double)csum);

    if (tid == 128) {
      float gx = tgt[t*7+2] * (float)GG, gyv = tgt[t*7+3] * (float)GG;
      float gw = tgt[t*7+4] * (float)GG, gh = tgt[t*7+5] * (float)GG;
      float ga = tgt[t*7+6];
      float rx = base[0], ry = base[(size_t)SS], rw = base[2*(size_t)SS],
            rh = base[3*(size_t)SS], ra = base[4*(size_t)SS], rcf = base[5*(size_t)SS];
      float aw = d_ma[bn][0], ah = d_ma[bn][1], aa = d_ma[bn][2];
      float px = sigm(rx)*1.05f - 0.025f + (float)gi;
      float py = sigm(ry)*1.05f - 0.025f + (float)gj;
      float pw = expf(rw)*aw, ph = expf(rh)*ah;
      float pang = ra + aa;
      float p1x = px - pw*0.5f, p1y = py - ph*0.5f, p2x = px + pw*0.5f, p2y = py + ph*0.5f;
      float t1x = gx - gw*0.5f, t1y = gyv - gh*0.5f, t2x = gx + gw*0.5f, t2y = gyv + gh*0.5f;
      float w1 = p2x - p1x, h1 = p2y - p1y, w2 = t2x - t1x, h2 = t2y - t1y;
      float area1 = w1*h1, area2 = w2*h2;
      float c1x = (p1x+p2x)*0.5f, c1y = (p1y+p2y)*0.5f, c2x = (t1x+t2x)*0.5f, c2y = (t1y+t2y)*0.5f;
      float ix = fmaxf(fminf(p2x,t2x) - fmaxf(p1x,t1x), 0.0f);
      float iy = fmaxf(fminf(p2y,t2y) - fmaxf(p1y,t1y), 0.0f);
      float inter_area = ix*iy;
      float dcx = c2x - c1x, dcy = c2y - c1y;
      float inter_diag = dcx*dcx + dcy*dcy;
      float ox = fmaxf(fmaxf(p2x,t2x) - fminf(p1x,t1x), 0.0f);
      float oy = fmaxf(fmaxf(p2y,t2y) - fminf(p1y,t1y), 0.0f);
      float outer_diag = ox*ox + oy*oy;
      float uni = area1 + area2 - inter_area;
      float u = inter_diag / outer_diag;
      float iou = inter_area / uni;
      float da = atanf(w2/h2) - atanf(w1/h1);
      float v = (float)(4.0/(PI_*PI_)) * da * da;
      float alpha = v / (1.0f - iou + v);
      float ciou = fminf(fmaxf(iou - (u + alpha*v), -1.0f), 1.0f);
      float skew_iou = iou * fabsf(cosf(pang - ga));
      float skew = expf(1.0f - skew_iou) - 1.0f;
      float bscale = 2.0f - gw*gh/369664.0f;   // (8*76)^2
      float ciou_t = bscale * (1.0f - ciou);
      float ta = ga - aa;
      float d = fabsf(ra - ta);
      float sl1 = (d < 1.0f) ? 0.5f*d*d : d - 0.5f;
      float reg = sl1 + ciou_t;
      atomicAdd(&acc[2], (double)(reg * (skew / reg)));
      float pc = sigm(rcf);
      float pcl = fminf(fmaxf(pc, 1e-7f), 1.0f - 1e-7f);
      float om = 1.0f - pc;
      atomicAdd(&acc[1], (double)(-logf(pcl) * 0.25f * om * om));
    }
    return;
  }

  // ---- conf part: noobj focal over all cells (channel 5), flag-gated ----
  __shared__ double wsum[4];
  int j = (blk - nT)*256 + tid;
  double fl = 0.0;
  if (j < NCONF4) {
    int ba = j / (SS/4);                 // plane index (b*NANC+a)
    int q  = j - ba*(SS/4);
    int spos = 4*q;
    const float4 v4 = *(const float4*)(in + (size_t)ba*CHN*SS + 5*(size_t)SS + spos);
    int cell0 = ba*SS + spos;
    unsigned word = flags[cell0 >> 5];
    int bbit = cell0 & 31;               // multiple of 4, bits in same word
    float pv[4] = {v4.x, v4.y, v4.z, v4.w};
    #pragma unroll
    for (int e = 0; e < 4; ++e) {
      if (!((word >> (bbit + e)) & 1u)) {
        float p = fsig(pv[e]);
        float pcl = fminf(fmaxf(p, 1e-7f), 1.0f - 1e-7f);
        fl += (double)(-__logf(1.0f - pcl) * 0.75f * p * p);
      }
    }
  }
  int lane = tid & 63, wid = tid >> 6;
  for (int off = 32; off; off >>= 1) fl += __shfl_down(fl, off);
  if (lane == 0) wsum[wid] = fl;
  __syncthreads();
  if (tid == 0) {
    double s = wsum[0] + wsum[1] + wsum[2] + wsum[3];
    if (s != 0.0) atomicAdd(&acc[0], s);
  }
}

// ---------------- K3: pure transpose/decode, 4 row-tiles per block, pipelined ----------------
// Store loop: per cell 21 aligned float4 + 1 float2 (single loop; each 64B line
// written by one wave). Channel-major LDS, b128 staging writes, reg prefetch.
__global__ __launch_bounds__(256) void k_main(const float* __restrict__ in,
                                              float* __restrict__ out) {
  __shared__ float lds[CHN * LSTR];      // 26488 B
  int blk = blockIdx.x;
  int tgrp = blk % TGRP;
  int ba = blk / TGRP;
  int a = ba % NANC;
  float aw8 = d_ma[a][0]*8.0f, ah8 = d_ma[a][1]*8.0f, aa = d_ma[a][2];
  const float* plane_in = in + (size_t)ba*CHN*SS;
  float* plane_out = out + (size_t)ba*SS*CHN;
  int tile0 = tgrp*TPB;

  float4 r[NLOAD];
  { const float* tin = plane_in + tile0*TILE;
    #pragma unroll
    for (int k = 0; k < NLOAD; ++k) {
      int i = threadIdx.x + k*256;
      if (i < TOT4) { int c = i/19, s4 = i - c*19;
        r[k] = *(const float4*)(tin + (size_t)c*SS + 4*s4); } }
  }

  for (int tt = 0; tt < TPB; ++tt) {
    int tile = tile0 + tt;
    __syncthreads();                     // prior store-loop LDS reads done
    #pragma unroll
    for (int k = 0; k < NLOAD; ++k) {
      int i = threadIdx.x + k*256;
      if (i < TOT4) {
        int c = i/19, s4 = i - c*19;
        float* p = &lds[c*LSTR + 4*s4];
        p[0] = r[k].x; p[1] = r[k].y; p[2] = r[k].z; p[3] = r[k].w;
      }
    }
    __syncthreads();
    if (tt + 1 < TPB) {                  // prefetch next tile into regs
      const float* tin = plane_in + (tile + 1)*TILE;
      #pragma unroll
      for (int k = 0; k < NLOAD; ++k) {
        int i = threadIdx.x + k*256;
        if (i < TOT4) { int c = i/19, s4 = i - c*19;
          r[k] = *(const float4*)(tin + (size_t)c*SS + 4*s4); } }
    }
    float gyf = (float)tile;
    float* orow = plane_out + (size_t)tile*TILE*CHN;
    // 22 items per cell: j<21 -> float4 at c = 2*(s&1)+4j ; j==21 -> float2 tail
    for (int q = threadIdx.x; q < TILE*22; q += 256) {
      int s = q / 22;
      int j = q - s*22;
      int par = s & 1;
      if (j < 21) {
        int c = 2*par + 4*j;
        float v0 = lds[(c  )*LSTR + s];
        float v1 = lds[(c+1)*LSTR + s];
        float v2 = lds[(c+2)*LSTR + s];
        float v3 = lds[(c+3)*LSTR + s];
        float4 R;
        if (c >= 6) {
          R = make_float4(fsig(v0), fsig(v1), fsig(v2), fsig(v3));
        } else if (c == 0) {             // even s: chans 0,1,2,3
          R.x = (fsig(v0)*1.05f - 0.025f + (float)s)*8.0f;
          R.y = (fsig(v1)*1.05f - 0.025f + gyf)*8.0f;
          R.z = __expf(v2)*aw8;
          R.w = __expf(v3)*ah8;
        } else if (c == 4) {             // even s: chans 4,5,6,7
          R.x = v0 + aa;
          R.y = fsig(v1);
          R.z = fsig(v2);
          R.w = fsig(v3);
        } else {                         // c==2, odd s: chans 2,3,4,5
          R.x = __expf(v0)*aw8;
          R.y = __expf(v1)*ah8;
          R.z = v2 + aa;
          R.w = fsig(v3);
        }
        *(float4*)(orow + s*CHN + c) = R;
      } else {
        int c = par ? 0 : 84;
        float v0 = lds[(c  )*LSTR + s];
        float v1 = lds[(c+1)*LSTR + s];
        float2 R;
        if (par) {                       // odd s: chans 0,1
          R.x = (fsig(v0)*1.05f - 0.025f + (float)s)*8.0f;
          R.y = (fsig(v1)*1.05f - 0.025f + gyf)*8.0f;
        } else {                         // even s: chans 84,85
          R = make_float2(fsig(v0), fsig(v1));
        }
        *(float2*)(orow + s*CHN + c) = R;
      }
    }
  }
}

// ---------------- K4: finalize loss ----------------
__global__ void k_fin(const double* __restrict__ acc, const int* __restrict__ cnt,
                      float* __restrict__ out) {
  double n_obj = fmax((double)cnt[1], 1.0);
  double n_noobj = fmax((double)(NCELL - cnt[0]), 1.0);
  double reg_loss = acc[2] / n_obj;
  double conf_loss = acc[1] / n_obj + acc[0] / n_noobj;
  double cls_loss = acc[3] / (n_obj * (double)NCLS);
  out[(size_t)NCELL * CHN] = (float)(reg_loss + 10.0*conf_loss + cls_loss);
}

extern "C" void kernel_launch(void* const* d_in, const int* in_sizes, int n_in,
                              void* d_out, int out_size, void* d_ws, size_t ws_size,
                              hipStream_t stream) {
  const float* in  = (const float*)d_in[0];
  const float* tgt = (const float*)d_in[1];
  float* out = (float*)d_out;
  double* acc = (double*)d_ws;
  int* cnt = (int*)((char*)d_ws + 32);
  int* win = (int*)((char*)d_ws + WS_WIN);
  int4* meta = (int4*)((char*)d_ws + WS_META);
  uint2* lm = (uint2*)((char*)d_ws + WS_LM);
  unsigned* flags = (unsigned*)((char*)d_ws + WS_FLAGS);
  int nT = in_sizes[1] / 7;
  if (nT > NT_MAX) nT = NT_MAX;

  hipLaunchKernelGGL(k_prep, dim3(1), dim3(256), 0, stream,
                     tgt, flags, win, meta, lm, cnt, acc, nT);
  hipLaunchKernelGGL(k_loss, dim3(nT + NCONFBLK), dim3(256), 0, stream,
                     tgt, in, win, meta, lm, flags, acc, nT);
  hipLaunchKernelGGL(k_fin, dim3(1), dim3(1), 0, stream, acc, cnt, out);
  hipLaunchKernelGGL(k_main, dim3(NB*NANC*TGRP), dim3(256), 0, stream, in, out);
}